// Round 8
// baseline (414.919 us; speedup 1.0000x reference)
//
#include <hip/hip_runtime.h>
#include <hip/hip_bf16.h>
#include <math.h>

#define R 2048
#define K 20
#define TOPK 100
#define SCORE_TH 0.5f
#define NMS_TH 0.5f
#define IMGW 1333.0f
#define IMGH 800.0f

typedef unsigned long long u64;
typedef unsigned int u32;

#define MAPF_MINF 0x007FFFFFu  // mapf(-inf)
#define MAPF_TH 0xBF000000u    // mapf(0.5f)

// Monotone map: float total order -> unsigned total order.
__device__ __forceinline__ u32 mapf(float f) {
  u32 b = __float_as_uint(f);
  return (b & 0x80000000u) ? ~b : (b | 0x80000000u);
}
__device__ __forceinline__ float unmapf(u32 u) {
  u32 b = (u & 0x80000000u) ? (u & 0x7FFFFFFFu) : ~u;
  return __uint_as_float(b);
}
__device__ __forceinline__ float4 clipbox(float4 b) {
  float4 o;
  o.x = fminf(fmaxf(b.x, 0.0f), IMGW);
  o.y = fminf(fmaxf(b.y, 0.0f), IMGH);
  o.z = fminf(fmaxf(b.z, 0.0f), IMGW);
  o.w = fminf(fmaxf(b.w, 0.0f), IMGH);
  return o;
}

// ---------------- sort: per-class bitonic (prep fused), 1024 threads ----------------
// Key: (mapf(valid ? s : -inf) << 32) | ~r  -> desc sort == score desc, r asc.
__global__ __launch_bounds__(1024) void sort_kernel(const float* __restrict__ scores,
                                                    const float* __restrict__ boxes,
                                                    u64* __restrict__ sortedkey,
                                                    float4* __restrict__ sboxs,
                                                    int* __restrict__ nvalid) {
  const int c = blockIdx.x;
  const int tid = threadIdx.x;
  __shared__ u64 sk[R];       // 16 KB
  __shared__ float4 cb[R];    // 32 KB
  for (int r = tid; r < R; r += 1024) {
    float4 b = reinterpret_cast<const float4*>(boxes)[r];
    bool fin = isfinite(b.x) && isfinite(b.y) && isfinite(b.z) && isfinite(b.w);
    float s = 0.0f;
    for (int c2 = 0; c2 < K + 1; ++c2) {
      float v = scores[r * (K + 1) + c2];
      fin = fin && isfinite(v);
      if (c2 == c) s = v;
    }
    cb[r] = clipbox(b);
    bool valid = (s > SCORE_TH) && fin;
    u32 hi = valid ? mapf(s) : MAPF_MINF;
    sk[r] = ((u64)hi << 32) | (u32)(~(u32)r);
  }
  __syncthreads();
  for (int k = 2; k <= R; k <<= 1) {
    for (int j = k >> 1; j > 0; j >>= 1) {
      for (int i = tid; i < R; i += 1024) {
        int ixj = i ^ j;
        if (ixj > i) {
          u64 a = sk[i], b = sk[ixj];
          bool sw = ((i & k) == 0) ? (a < b) : (a > b);
          if (sw) { sk[i] = b; sk[ixj] = a; }
        }
      }
      __syncthreads();
    }
  }
  u64* skg = sortedkey + (size_t)c * R;
  float4* sbg = sboxs + (size_t)c * R;
  for (int i = tid; i < R; i += 1024) {
    u64 key = sk[i];
    skg[i] = key;
    u32 r = (~(u32)key) & 2047u;
    sbg[i] = cb[r];
    bool vi = ((u32)(key >> 32)) > MAPF_TH;
    if (i == 0 && !vi) nvalid[c] = 0;
    if (vi) {
      bool vlast = (i == R - 1);
      bool vn = vlast ? false : (((u32)(sk[i + 1] >> 32)) > MAPF_TH);
      if (vlast || !vn) nvalid[c] = i + 1;
    }
  }
}

// ---------------- mask: suppression bit-matrix (sorted-index space) ----------------
// mask[c][i][w] bit b: j = 64w+b, j > i, iou(i,j) > TH.  Rows >= nv never read.
__global__ __launch_bounds__(1024) void mask_kernel(const float4* __restrict__ sboxs,
                                                    const int* __restrict__ nvalid,
                                                    u64* __restrict__ maskbuf) {
  const int c = blockIdx.x;
  const int tid = threadIdx.x;
  const int lane = tid & 63;
  const int wave = tid >> 6;  // 0..15
  __shared__ float4 sb[R];
  __shared__ float sa[R];
  const float4* sbg = sboxs + (size_t)c * R;
  const int nv = nvalid[c];
  for (int i = tid; i < R; i += 1024) {
    float4 b = sbg[i];
    sb[i] = b;
    sa[i] = (b.z - b.x) * (b.w - b.y);
  }
  __syncthreads();
  const int wend = (nv + 63) >> 6;
  u64* mrowbase = maskbuf + (size_t)c * R * 32;
  for (int row = blockIdx.y * 16 + wave; row < nv; row += 128) {
    float4 b = sb[row];
    float ai = sa[row];
    u64 myword = 0;
    int wstart = row >> 6;
    for (int w = wstart; w < wend; ++w) {
      int col = (w << 6) + lane;
      float4 q = sb[col];
      float lx = fmaxf(b.x, q.x), ly = fmaxf(b.y, q.y);
      float rx = fminf(b.z, q.z), ry = fminf(b.w, q.w);
      float ww = fmaxf(rx - lx, 0.0f), hh = fmaxf(ry - ly, 0.0f);
      float inter = ww * hh;
      float uni = ai + sa[col] - inter;
      bool bit = (col > row) && (inter / fmaxf(uni, 1e-9f) > NMS_TH);
      u64 word = __ballot(bit);
      if (lane == w) myword = word;  // lane w keeps word w (w < 32)
    }
    u64* mrow = mrowbase + (size_t)row * 32;
    if (lane < 32) mrow[lane] = myword;  // words outside [wstart,wend) are 0
  }
}

// ---------------- scan: sequential greedy (round-6-proven logic), LDS windows ------
// Exact per-row chain: wv = shfl(remv, i>>6); keep = !bit; if kept OR mask row.
// Mask rows come from a double-buffered LDS window (next 64 rows staged while the
// current 64 are processed); rows only read when kept.
__global__ __launch_bounds__(64) void scan_kernel(const u64* __restrict__ sortedkey,
                                                  const int* __restrict__ nvalid,
                                                  const u64* __restrict__ maskbuf,
                                                  u64* __restrict__ cand,
                                                  int* __restrict__ nkept,
                                                  u32* __restrict__ keepbm) {
  const int c = blockIdx.x;
  const int lane = threadIdx.x;
  const int nv = nvalid[c];
  const u64* mb = maskbuf + (size_t)c * R * 32;
  const u64* skg = sortedkey + (size_t)c * R;
  __shared__ u64 win[2][2048];  // [buf][(row&63)*32 + word], 2 x 16 KB
  __shared__ u64 keepw[32];
  __shared__ int pref[32];
  __shared__ u64 lcand[128];
  __shared__ u32 bm[64];
  if (lane < 32) keepw[lane] = 0;
  bm[lane] = 0;
  lcand[lane] = 0;
  lcand[lane + 64] = 0;

  const int ngroups = (nv + 63) >> 6;
  // Prologue: stage window 0 (rows 0..min(64,nv)-1), coalesced.
  if (ngroups > 0) {
    int lim = (nv < 64 ? nv : 64) * 32;
    for (int t = lane; t < 2048; t += 64) win[0][t] = (t < lim) ? mb[t] : 0;
  }
  __syncthreads();

  u64 remv = 0, keepm = 0;
  for (int g = 0; g < ngroups; ++g) {
    const int buf = g & 1;
    // Stage next window into the other buffer (issued before processing so the
    // global loads fly under the serial chain; no sync needed until loop end).
    if (g + 1 < ngroups) {
      int base = (g + 1) << 6;
      int nrows = nv - base; if (nrows > 64) nrows = 64;
      int lim = nrows * 32;
      for (int t = lane; t < 2048; t += 64)
        win[buf ^ 1][t] = (t < lim) ? mb[(size_t)base * 32 + t] : 0;
    }
    const int rb = g << 6;
    int rend = nv - rb; if (rend > 64) rend = 64;
    for (int b = 0; b < rend; ++b) {
      u64 wv = __shfl(remv, g, 64);  // word g of distributed remv (lane g owns it)
      bool keep = !((wv >> b) & 1ull);
      if (keep) {
        u64 v = (lane < 32) ? win[buf][b * 32 + lane] : 0;  // LDS, kept rows only
        remv |= v;
        if (lane == g) keepm |= (1ull << b);
      }
    }
    __syncthreads();  // next window fully staged; current buffer free for reuse
  }
  if (lane < 32) keepw[lane] = keepm;
  __syncthreads();
  if (lane == 0) {
    int run = 0;
    for (int g = 0; g < ngroups; ++g) { pref[g] = run; run += (int)__popcll(keepw[g]); }
    nkept[c] = run;
  }
  __syncthreads();
  // Emit compacted kept keys, re-encoded with ~flat (class + row) in the low word.
  for (int g = 0; g < ngroups; ++g) {
    u64 kw = keepw[g];
    if ((kw >> lane) & 1ull) {
      u64 below = lane ? (kw & ((1ull << lane) - 1ull)) : 0ull;
      int slot = pref[g] + (int)__popcll(below);
      u64 key = skg[(g << 6) + lane];
      u32 r = (~(u32)key) & 2047u;
      u32 flat = (u32)c * R + r;
      atomicOr(&bm[r >> 5], 1u << (r & 31));
      if (slot < 128) lcand[slot] = (key & 0xFFFFFFFF00000000ull) | (u64)(u32)(~flat);
    }
  }
  __syncthreads();
  cand[(size_t)c * 128 + lane] = lcand[lane];
  cand[(size_t)c * 128 + 64 + lane] = lcand[lane + 64];
  keepbm[c * 64 + lane] = bm[lane];
}

// ---------------- final: sort 2560 candidates (pad 4096), write outputs ----------------
__global__ __launch_bounds__(1024) void final_kernel(const u64* __restrict__ cand,
                                                     const int* __restrict__ nkept,
                                                     const u32* __restrict__ keepbm,
                                                     const float* __restrict__ boxes,
                                                     float* __restrict__ out) {
  const int tid = threadIdx.x;
  __shared__ u64 s[4096];  // 32 KB
  __shared__ int nk_sh;
  for (int i = tid; i < 4096; i += 1024) s[i] = (i < K * 128) ? cand[i] : 0ULL;
  if (tid == 0) {
    int nk = 0;
    for (int c = 0; c < K; ++c) nk += nkept[c];
    nk_sh = nk;
  }
  __syncthreads();
  for (int k = 2; k <= 4096; k <<= 1) {
    for (int j = k >> 1; j > 0; j >>= 1) {
      for (int i = tid; i < 4096; i += 1024) {
        int ixj = i ^ j;
        if (ixj > i) {
          u64 a = s[i], b = s[ixj];
          bool sw = ((i & k) == 0) ? (a < b) : (a > b);
          if (sw) { s[i] = b; s[ixj] = a; }
        }
      }
      __syncthreads();
    }
  }
  const int nk = nk_sh;
  if (nk >= TOPK) {
    if (tid < TOPK) {
      u64 key = s[tid];
      u32 flat = ~(u32)key;
      int c = (int)(flat >> 11);
      int r = (int)(flat & 2047);
      float4 b = clipbox(reinterpret_cast<const float4*>(boxes)[r]);
      out[tid] = unmapf((u32)(key >> 32));
      out[100 + 4 * tid + 0] = b.x;
      out[100 + 4 * tid + 1] = b.y;
      out[100 + 4 * tid + 2] = b.z;
      out[100 + 4 * tid + 3] = b.w;
      out[500 + tid] = (float)c;
      out[600 + tid] = (float)r;
    }
  } else {
    // Cold path (not expected on this input): exact -inf padding, flat asc.
    if (tid < nk) {
      u64 key = s[tid];
      u32 flat = ~(u32)key;
      int c = (int)(flat >> 11);
      int r = (int)(flat & 2047);
      float4 b = clipbox(reinterpret_cast<const float4*>(boxes)[r]);
      out[tid] = unmapf((u32)(key >> 32));
      out[100 + 4 * tid + 0] = b.x;
      out[100 + 4 * tid + 1] = b.y;
      out[100 + 4 * tid + 2] = b.z;
      out[100 + 4 * tid + 3] = b.w;
      out[500 + tid] = (float)c;
      out[600 + tid] = (float)r;
    }
    if (tid == 0) {
      int w = nk;
      for (u32 f = 0; f < (u32)(K * R) && w < TOPK; ++f) {
        u32 cc = f >> 11, rr = f & 2047u;
        if (!((keepbm[cc * 64 + (rr >> 5)] >> (rr & 31)) & 1u)) {
          float4 b = clipbox(reinterpret_cast<const float4*>(boxes)[rr]);
          out[w] = -INFINITY;
          out[100 + 4 * w + 0] = b.x;
          out[100 + 4 * w + 1] = b.y;
          out[100 + 4 * w + 2] = b.z;
          out[100 + 4 * w + 3] = b.w;
          out[500 + w] = (float)cc;
          out[600 + w] = (float)rr;
          ++w;
        }
      }
    }
  }
}

extern "C" void kernel_launch(void* const* d_in, const int* in_sizes, int n_in,
                              void* d_out, int out_size, void* d_ws, size_t ws_size,
                              hipStream_t stream) {
  const float* boxes = (const float*)d_in[0];
  const float* scores = (const float*)d_in[1];
  float* out = (float*)d_out;
  char* ws = (char*)d_ws;
  // Workspace layout (~11.6 MB; ws_size >= 11.9 MB confirmed in round 6):
  u64* sortedkey = (u64*)(ws + 0);          //    327680 B (20*2048*8)
  float4* sboxs = (float4*)(ws + 327680);   //    655360 B (20*2048*16)
  int* nvalid = (int*)(ws + 983040);        //       256 B
  u64* maskbuf = (u64*)(ws + 1048576);      //  10485760 B (20*2048*32*8)
  u64* cand = (u64*)(ws + 11534336);        //     20480 B (20*128*8)
  int* nkept = (int*)(ws + 11554816);       //       256 B
  u32* keepbm = (u32*)(ws + 11555072);      //      5120 B (20*64*4)
  (void)in_sizes; (void)n_in; (void)out_size; (void)ws_size;

  sort_kernel<<<K, 1024, 0, stream>>>(scores, boxes, sortedkey, sboxs, nvalid);
  mask_kernel<<<dim3(K, 8), 1024, 0, stream>>>(sboxs, nvalid, maskbuf);
  scan_kernel<<<K, 64, 0, stream>>>(sortedkey, nvalid, maskbuf, cand, nkept, keepbm);
  final_kernel<<<1, 1024, 0, stream>>>(cand, nkept, keepbm, boxes, out);
}

// Round 9
// 412.759 us; speedup vs baseline: 1.0052x; 1.0052x over previous
//
#include <hip/hip_runtime.h>
#include <hip/hip_bf16.h>
#include <math.h>

#define R 2048
#define K 20
#define TOPK 100
#define SCORE_TH 0.5f
#define NMS_TH 0.5f
#define IMGW 1333.0f
#define IMGH 800.0f

typedef unsigned long long u64;
typedef unsigned int u32;

#define MAPF_MINF 0x007FFFFFu  // mapf(-inf)
#define MAPF_TH 0xBF000000u    // mapf(0.5f)

// Monotone map: float total order -> unsigned total order.
__device__ __forceinline__ u32 mapf(float f) {
  u32 b = __float_as_uint(f);
  return (b & 0x80000000u) ? ~b : (b | 0x80000000u);
}
__device__ __forceinline__ float unmapf(u32 u) {
  u32 b = (u & 0x80000000u) ? (u & 0x7FFFFFFFu) : ~u;
  return __uint_as_float(b);
}
__device__ __forceinline__ float4 clipbox(float4 b) {
  float4 o;
  o.x = fminf(fmaxf(b.x, 0.0f), IMGW);
  o.y = fminf(fmaxf(b.y, 0.0f), IMGH);
  o.z = fminf(fmaxf(b.z, 0.0f), IMGW);
  o.w = fminf(fmaxf(b.w, 0.0f), IMGH);
  return o;
}

// ---------------- sort: per-class bitonic (prep fused), 1024 threads ----------------
// Key: (mapf(valid ? s : -inf) << 32) | ~r  -> desc sort == score desc, r asc.
__global__ __launch_bounds__(1024) void sort_kernel(const float* __restrict__ scores,
                                                    const float* __restrict__ boxes,
                                                    u64* __restrict__ sortedkey,
                                                    float4* __restrict__ sboxs,
                                                    int* __restrict__ nvalid) {
  const int c = blockIdx.x;
  const int tid = threadIdx.x;
  __shared__ u64 sk[R];       // 16 KB
  __shared__ float4 cb[R];    // 32 KB
  for (int r = tid; r < R; r += 1024) {
    float4 b = reinterpret_cast<const float4*>(boxes)[r];
    bool fin = isfinite(b.x) && isfinite(b.y) && isfinite(b.z) && isfinite(b.w);
    float s = 0.0f;
    for (int c2 = 0; c2 < K + 1; ++c2) {
      float v = scores[r * (K + 1) + c2];
      fin = fin && isfinite(v);
      if (c2 == c) s = v;
    }
    cb[r] = clipbox(b);
    bool valid = (s > SCORE_TH) && fin;
    u32 hi = valid ? mapf(s) : MAPF_MINF;
    sk[r] = ((u64)hi << 32) | (u32)(~(u32)r);
  }
  __syncthreads();
  for (int k = 2; k <= R; k <<= 1) {
    for (int j = k >> 1; j > 0; j >>= 1) {
      for (int i = tid; i < R; i += 1024) {
        int ixj = i ^ j;
        if (ixj > i) {
          u64 a = sk[i], b = sk[ixj];
          bool sw = ((i & k) == 0) ? (a < b) : (a > b);
          if (sw) { sk[i] = b; sk[ixj] = a; }
        }
      }
      __syncthreads();
    }
  }
  u64* skg = sortedkey + (size_t)c * R;
  float4* sbg = sboxs + (size_t)c * R;
  for (int i = tid; i < R; i += 1024) {
    u64 key = sk[i];
    skg[i] = key;
    u32 r = (~(u32)key) & 2047u;
    sbg[i] = cb[r];
    bool vi = ((u32)(key >> 32)) > MAPF_TH;
    if (i == 0 && !vi) nvalid[c] = 0;
    if (vi) {
      bool vlast = (i == R - 1);
      bool vn = vlast ? false : (((u32)(sk[i + 1] >> 32)) > MAPF_TH);
      if (vlast || !vn) nvalid[c] = i + 1;
    }
  }
}

// ---------------- mask: suppression bit-matrix (sorted-index space) ----------------
// mask[c][i][w] bit b: j = 64w+b, j > i, iou(i,j) > TH.  Rows >= nv never read.
__global__ __launch_bounds__(1024) void mask_kernel(const float4* __restrict__ sboxs,
                                                    const int* __restrict__ nvalid,
                                                    u64* __restrict__ maskbuf) {
  const int c = blockIdx.x;
  const int tid = threadIdx.x;
  const int lane = tid & 63;
  const int wave = tid >> 6;  // 0..15
  __shared__ float4 sb[R];
  __shared__ float sa[R];
  const float4* sbg = sboxs + (size_t)c * R;
  const int nv = nvalid[c];
  for (int i = tid; i < R; i += 1024) {
    float4 b = sbg[i];
    sb[i] = b;
    sa[i] = (b.z - b.x) * (b.w - b.y);
  }
  __syncthreads();
  const int wend = (nv + 63) >> 6;
  u64* mrowbase = maskbuf + (size_t)c * R * 32;
  for (int row = blockIdx.y * 16 + wave; row < nv; row += 128) {
    float4 b = sb[row];
    float ai = sa[row];
    u64 myword = 0;
    int wstart = row >> 6;
    for (int w = wstart; w < wend; ++w) {
      int col = (w << 6) + lane;
      float4 q = sb[col];
      float lx = fmaxf(b.x, q.x), ly = fmaxf(b.y, q.y);
      float rx = fminf(b.z, q.z), ry = fminf(b.w, q.w);
      float ww = fmaxf(rx - lx, 0.0f), hh = fmaxf(ry - ly, 0.0f);
      float inter = ww * hh;
      float uni = ai + sa[col] - inter;
      bool bit = (col > row) && (inter / fmaxf(uni, 1e-9f) > NMS_TH);
      u64 word = __ballot(bit);
      if (lane == w) myword = word;  // lane w keeps word w (w < 32)
    }
    u64* mrow = mrowbase + (size_t)row * 32;
    if (lane < 32) mrow[lane] = myword;  // words outside [wstart,wend) are 0
  }
}

// ---------------- scan: sequential greedy, register-replicated group word ----------
// Exact greedy semantics (bit-identical to round-8's proven loop): suppression of
// row b = (cross-group word at group start) OR (intra words of prior kept rows in
// this group). Per-row chain is register-only; one shfl per KEPT row; one shfl +
// one (bank-conflicted, once) LDS preload per group. Kept rows' full mask rows OR
// into the distributed acc (lane w owns word w) off the chain (consumed only by
// next group's shfl).
__global__ __launch_bounds__(64) void scan_kernel(const u64* __restrict__ sortedkey,
                                                  const int* __restrict__ nvalid,
                                                  const u64* __restrict__ maskbuf,
                                                  u64* __restrict__ cand,
                                                  int* __restrict__ nkept,
                                                  u32* __restrict__ keepbm) {
  const int c = blockIdx.x;
  const int lane = threadIdx.x;
  const int nv = nvalid[c];
  const u64* mb = maskbuf + (size_t)c * R * 32;
  const u64* skg = sortedkey + (size_t)c * R;
  __shared__ u64 win[2][2048];  // [buf][(row&63)*32 + word], 2 x 16 KB
  __shared__ u64 keepw[32];
  __shared__ int pref[32];
  __shared__ u64 lcand[128];
  __shared__ u32 bm[64];
  if (lane < 32) keepw[lane] = 0;
  bm[lane] = 0;
  lcand[lane] = 0;
  lcand[lane + 64] = 0;

  const int ngroups = (nv + 63) >> 6;
  // Prologue: stage window 0 (rows 0..min(64,nv)-1), coalesced.
  if (ngroups > 0) {
    int lim = (nv < 64 ? nv : 64) * 32;
    for (int t = lane; t < 2048; t += 64) win[0][t] = (t < lim) ? mb[t] : 0;
  }
  __syncthreads();

  u64 acc = 0;  // distributed suppression bitmap: lane w (<32) owns word w
  for (int g = 0; g < ngroups; ++g) {
    const int buf = g & 1;
    // Stage next window (global loads fly under this group's serial chain).
    if (g + 1 < ngroups) {
      int base = (g + 1) << 6;
      int nrows = nv - base; if (nrows > 64) nrows = 64;
      int lim = nrows * 32;
      for (int t = lane; t < 2048; t += 64)
        win[buf ^ 1][t] = (t < lim) ? mb[(size_t)base * 32 + t] : 0;
    }
    const int rb = g << 6;
    int rend = nv - rb; if (rend > 64) rend = 64;
    u64 rg = __shfl(acc, g, 64);                          // 1 shfl / group
    u64 myintra = (lane < rend) ? win[buf][lane * 32 + g] : 0;  // row rb+lane, word g
    u64 keep = 0;
    for (int b = 0; b < rend; ++b) {
      if (!((rg >> b) & 1ull)) {            // register-only test (rg wave-uniform)
        keep |= (1ull << b);
        rg |= __shfl(myintra, b, 64);       // intra suppressions of kept row b (bits > b)
        if (lane < 32) acc |= win[buf][b * 32 + lane];  // off-chain full-row OR
      }
    }
    if (lane == 0) keepw[g] = keep;
    __syncthreads();  // next window fully staged; current buffer reusable
  }
  __syncthreads();
  if (lane == 0) {
    int run = 0;
    for (int g = 0; g < ngroups; ++g) { pref[g] = run; run += (int)__popcll(keepw[g]); }
    nkept[c] = run;
  }
  __syncthreads();
  // Emit compacted kept keys, re-encoded with ~flat (class + row) in the low word.
  for (int g = 0; g < ngroups; ++g) {
    u64 kw = keepw[g];
    if ((kw >> lane) & 1ull) {
      u64 below = lane ? (kw & ((1ull << lane) - 1ull)) : 0ull;
      int slot = pref[g] + (int)__popcll(below);
      u64 key = skg[(g << 6) + lane];
      u32 r = (~(u32)key) & 2047u;
      u32 flat = (u32)c * R + r;
      atomicOr(&bm[r >> 5], 1u << (r & 31));
      if (slot < 128) lcand[slot] = (key & 0xFFFFFFFF00000000ull) | (u64)(u32)(~flat);
    }
  }
  __syncthreads();
  cand[(size_t)c * 128 + lane] = lcand[lane];
  cand[(size_t)c * 128 + 64 + lane] = lcand[lane + 64];
  keepbm[c * 64 + lane] = bm[lane];
}

// ---------------- final: sort 2560 candidates (pad 4096), write outputs ----------------
__global__ __launch_bounds__(1024) void final_kernel(const u64* __restrict__ cand,
                                                     const int* __restrict__ nkept,
                                                     const u32* __restrict__ keepbm,
                                                     const float* __restrict__ boxes,
                                                     float* __restrict__ out) {
  const int tid = threadIdx.x;
  __shared__ u64 s[4096];  // 32 KB
  __shared__ int nk_sh;
  for (int i = tid; i < 4096; i += 1024) s[i] = (i < K * 128) ? cand[i] : 0ULL;
  if (tid == 0) {
    int nk = 0;
    for (int c = 0; c < K; ++c) nk += nkept[c];
    nk_sh = nk;
  }
  __syncthreads();
  for (int k = 2; k <= 4096; k <<= 1) {
    for (int j = k >> 1; j > 0; j >>= 1) {
      for (int i = tid; i < 4096; i += 1024) {
        int ixj = i ^ j;
        if (ixj > i) {
          u64 a = s[i], b = s[ixj];
          bool sw = ((i & k) == 0) ? (a < b) : (a > b);
          if (sw) { s[i] = b; s[ixj] = a; }
        }
      }
      __syncthreads();
    }
  }
  const int nk = nk_sh;
  if (nk >= TOPK) {
    if (tid < TOPK) {
      u64 key = s[tid];
      u32 flat = ~(u32)key;
      int c = (int)(flat >> 11);
      int r = (int)(flat & 2047);
      float4 b = clipbox(reinterpret_cast<const float4*>(boxes)[r]);
      out[tid] = unmapf((u32)(key >> 32));
      out[100 + 4 * tid + 0] = b.x;
      out[100 + 4 * tid + 1] = b.y;
      out[100 + 4 * tid + 2] = b.z;
      out[100 + 4 * tid + 3] = b.w;
      out[500 + tid] = (float)c;
      out[600 + tid] = (float)r;
    }
  } else {
    // Cold path (not expected on this input): exact -inf padding, flat asc.
    if (tid < nk) {
      u64 key = s[tid];
      u32 flat = ~(u32)key;
      int c = (int)(flat >> 11);
      int r = (int)(flat & 2047);
      float4 b = clipbox(reinterpret_cast<const float4*>(boxes)[r]);
      out[tid] = unmapf((u32)(key >> 32));
      out[100 + 4 * tid + 0] = b.x;
      out[100 + 4 * tid + 1] = b.y;
      out[100 + 4 * tid + 2] = b.z;
      out[100 + 4 * tid + 3] = b.w;
      out[500 + tid] = (float)c;
      out[600 + tid] = (float)r;
    }
    if (tid == 0) {
      int w = nk;
      for (u32 f = 0; f < (u32)(K * R) && w < TOPK; ++f) {
        u32 cc = f >> 11, rr = f & 2047u;
        if (!((keepbm[cc * 64 + (rr >> 5)] >> (rr & 31)) & 1u)) {
          float4 b = clipbox(reinterpret_cast<const float4*>(boxes)[rr]);
          out[w] = -INFINITY;
          out[100 + 4 * w + 0] = b.x;
          out[100 + 4 * w + 1] = b.y;
          out[100 + 4 * w + 2] = b.z;
          out[100 + 4 * w + 3] = b.w;
          out[500 + w] = (float)cc;
          out[600 + w] = (float)rr;
          ++w;
        }
      }
    }
  }
}

extern "C" void kernel_launch(void* const* d_in, const int* in_sizes, int n_in,
                              void* d_out, int out_size, void* d_ws, size_t ws_size,
                              hipStream_t stream) {
  const float* boxes = (const float*)d_in[0];
  const float* scores = (const float*)d_in[1];
  float* out = (float*)d_out;
  char* ws = (char*)d_ws;
  // Workspace layout (~11.6 MB; ws_size >= 11.9 MB confirmed in round 6):
  u64* sortedkey = (u64*)(ws + 0);          //    327680 B (20*2048*8)
  float4* sboxs = (float4*)(ws + 327680);   //    655360 B (20*2048*16)
  int* nvalid = (int*)(ws + 983040);        //       256 B
  u64* maskbuf = (u64*)(ws + 1048576);      //  10485760 B (20*2048*32*8)
  u64* cand = (u64*)(ws + 11534336);        //     20480 B (20*128*8)
  int* nkept = (int*)(ws + 11554816);       //       256 B
  u32* keepbm = (u32*)(ws + 11555072);      //      5120 B (20*64*4)
  (void)in_sizes; (void)n_in; (void)out_size; (void)ws_size;

  sort_kernel<<<K, 1024, 0, stream>>>(scores, boxes, sortedkey, sboxs, nvalid);
  mask_kernel<<<dim3(K, 8), 1024, 0, stream>>>(sboxs, nvalid, maskbuf);
  scan_kernel<<<K, 64, 0, stream>>>(sortedkey, nvalid, maskbuf, cand, nkept, keepbm);
  final_kernel<<<1, 1024, 0, stream>>>(cand, nkept, keepbm, boxes, out);
}

// Round 10
// 333.899 us; speedup vs baseline: 1.2426x; 1.2362x over previous
//
#include <hip/hip_runtime.h>
#include <hip/hip_bf16.h>
#include <math.h>

#define R 2048
#define K 20
#define TOPK 100
#define SCORE_TH 0.5f
#define NMS_TH 0.5f
#define IMGW 1333.0f
#define IMGH 800.0f

typedef unsigned long long u64;
typedef unsigned int u32;

#define MAPF_MINF 0x007FFFFFu  // mapf(-inf)
#define MAPF_TH 0xBF000000u    // mapf(0.5f)

// Monotone map: float total order -> unsigned total order.
__device__ __forceinline__ u32 mapf(float f) {
  u32 b = __float_as_uint(f);
  return (b & 0x80000000u) ? ~b : (b | 0x80000000u);
}
__device__ __forceinline__ float unmapf(u32 u) {
  u32 b = (u & 0x80000000u) ? (u & 0x7FFFFFFFu) : ~u;
  return __uint_as_float(b);
}
__device__ __forceinline__ float4 clipbox(float4 b) {
  float4 o;
  o.x = fminf(fmaxf(b.x, 0.0f), IMGW);
  o.y = fminf(fmaxf(b.y, 0.0f), IMGH);
  o.z = fminf(fmaxf(b.z, 0.0f), IMGW);
  o.w = fminf(fmaxf(b.w, 0.0f), IMGH);
  return o;
}

// ---------------- sort: per-class bitonic (prep fused), 1024 threads ----------------
// Key: (mapf(valid ? s : -inf) << 32) | ~r  -> desc sort == score desc, r asc.
__global__ __launch_bounds__(1024) void sort_kernel(const float* __restrict__ scores,
                                                    const float* __restrict__ boxes,
                                                    u64* __restrict__ sortedkey,
                                                    float4* __restrict__ sboxs,
                                                    int* __restrict__ nvalid) {
  const int c = blockIdx.x;
  const int tid = threadIdx.x;
  __shared__ u64 sk[R];       // 16 KB
  __shared__ float4 cb[R];    // 32 KB
  for (int r = tid; r < R; r += 1024) {
    float4 b = reinterpret_cast<const float4*>(boxes)[r];
    bool fin = isfinite(b.x) && isfinite(b.y) && isfinite(b.z) && isfinite(b.w);
    float s = 0.0f;
    for (int c2 = 0; c2 < K + 1; ++c2) {
      float v = scores[r * (K + 1) + c2];
      fin = fin && isfinite(v);
      if (c2 == c) s = v;
    }
    cb[r] = clipbox(b);
    bool valid = (s > SCORE_TH) && fin;
    u32 hi = valid ? mapf(s) : MAPF_MINF;
    sk[r] = ((u64)hi << 32) | (u32)(~(u32)r);
  }
  __syncthreads();
  for (int k = 2; k <= R; k <<= 1) {
    for (int j = k >> 1; j > 0; j >>= 1) {
      for (int i = tid; i < R; i += 1024) {
        int ixj = i ^ j;
        if (ixj > i) {
          u64 a = sk[i], b = sk[ixj];
          bool sw = ((i & k) == 0) ? (a < b) : (a > b);
          if (sw) { sk[i] = b; sk[ixj] = a; }
        }
      }
      __syncthreads();
    }
  }
  u64* skg = sortedkey + (size_t)c * R;
  float4* sbg = sboxs + (size_t)c * R;
  for (int i = tid; i < R; i += 1024) {
    u64 key = sk[i];
    skg[i] = key;
    u32 r = (~(u32)key) & 2047u;
    sbg[i] = cb[r];
    bool vi = ((u32)(key >> 32)) > MAPF_TH;
    if (i == 0 && !vi) nvalid[c] = 0;
    if (vi) {
      bool vlast = (i == R - 1);
      bool vn = vlast ? false : (((u32)(sk[i + 1] >> 32)) > MAPF_TH);
      if (vlast || !vn) nvalid[c] = i + 1;
    }
  }
}

// ---------------- mask: suppression bit-matrix (sorted-index space) ----------------
// mask[c][i][w] bit b: j = 64w+b, j > i, iou(i,j) > TH.  Rows >= nv never read.
__global__ __launch_bounds__(1024) void mask_kernel(const float4* __restrict__ sboxs,
                                                    const int* __restrict__ nvalid,
                                                    u64* __restrict__ maskbuf) {
  const int c = blockIdx.x;
  const int tid = threadIdx.x;
  const int lane = tid & 63;
  const int wave = tid >> 6;  // 0..15
  __shared__ float4 sb[R];
  __shared__ float sa[R];
  const float4* sbg = sboxs + (size_t)c * R;
  const int nv = nvalid[c];
  for (int i = tid; i < R; i += 1024) {
    float4 b = sbg[i];
    sb[i] = b;
    sa[i] = (b.z - b.x) * (b.w - b.y);
  }
  __syncthreads();
  const int wend = (nv + 63) >> 6;
  u64* mrowbase = maskbuf + (size_t)c * R * 32;
  for (int row = blockIdx.y * 16 + wave; row < nv; row += 128) {
    float4 b = sb[row];
    float ai = sa[row];
    u64 myword = 0;
    int wstart = row >> 6;
    for (int w = wstart; w < wend; ++w) {
      int col = (w << 6) + lane;
      float4 q = sb[col];
      float lx = fmaxf(b.x, q.x), ly = fmaxf(b.y, q.y);
      float rx = fminf(b.z, q.z), ry = fminf(b.w, q.w);
      float ww = fmaxf(rx - lx, 0.0f), hh = fmaxf(ry - ly, 0.0f);
      float inter = ww * hh;
      float uni = ai + sa[col] - inter;
      bool bit = (col > row) && (inter / fmaxf(uni, 1e-9f) > NMS_TH);
      u64 word = __ballot(bit);
      if (lane == w) myword = word;  // lane w keeps word w (w < 32)
    }
    u64* mrow = mrowbase + (size_t)row * 32;
    if (lane < 32) mrow[lane] = myword;  // words outside [wstart,wend) are 0
  }
}

// ---------------- scan: sequential greedy, no LDS staging, deferred batch ORs ------
// Bit-identical greedy semantics (round-9-proven inner loop): suppression of row b
// = (cross-group word at group start) OR (intra words of prior kept rows in this
// group, via register shfl). Cross-group ORs of kept rows' full mask rows are
// deferred to group end and batched 4-wide (independent global loads in flight);
// greedy only consults them at the next group boundary, so order is preserved.
__global__ __launch_bounds__(64) void scan_kernel(const u64* __restrict__ sortedkey,
                                                  const int* __restrict__ nvalid,
                                                  const u64* __restrict__ maskbuf,
                                                  u64* __restrict__ cand,
                                                  int* __restrict__ nkept,
                                                  u32* __restrict__ keepbm) {
  const int c = blockIdx.x;
  const int lane = threadIdx.x;
  const int nv = nvalid[c];
  const u64* mb = maskbuf + (size_t)c * R * 32;
  const u64* skg = sortedkey + (size_t)c * R;
  __shared__ u64 keepw[32];
  __shared__ int pref[32];
  __shared__ u64 lcand[128];
  __shared__ u32 bm[64];
  if (lane < 32) keepw[lane] = 0;
  bm[lane] = 0;
  lcand[lane] = 0;
  lcand[lane + 64] = 0;
  __syncthreads();

  const int ngroups = (nv + 63) >> 6;
  // acc distributed: lane w (<32) owns suppression word w, split over 4 registers
  // so batched ORs pipeline (named slots, compile-time indexed -> stay in VGPRs).
  u64 acc0 = 0, acc1 = 0, acc2 = 0, acc3 = 0;
  // Prefetch group 0's intra words: row lane's word 0.
  int nr0 = (nv < 64) ? nv : 64;
  u64 intra_cur = (ngroups > 0 && lane < nr0) ? mb[(size_t)lane * 32 + 0] : 0;

  for (int g = 0; g < ngroups; ++g) {
    const int rb = g << 6;
    int rend = nv - rb; if (rend > 64) rend = 64;
    // Prefetch next group's intra words (off-chain; consumed next iteration).
    u64 intra_nxt = 0;
    if (g + 1 < ngroups) {
      int base = (g + 1) << 6;
      int nr = nv - base; if (nr > 64) nr = 64;
      intra_nxt = (lane < nr) ? mb[(size_t)(base + lane) * 32 + (g + 1)] : 0;
    }
    // Cross-group suppression word for this group (uniform after shfl).
    u64 rg = __shfl(acc0 | acc1 | acc2 | acc3, g, 64);
    u64 keep = 0;
    for (int b = 0; b < rend; ++b) {        // proven serial loop: register-only tests
      if (!((rg >> b) & 1ull)) {
        keep |= (1ull << b);
        rg |= __shfl(intra_cur, b, 64);     // intra suppressions of kept row b (bits > b)
      }
    }
    if (lane == 0) keepw[g] = keep;
    // Deferred cross-group ORs: batch kept rows' full mask rows, 4 loads in flight.
    u64 kb = keep;
    while (kb) {
      int b0 = __builtin_ctzll(kb); kb &= kb - 1;
      int b1 = -1, b2 = -1, b3 = -1;
      if (kb) { b1 = __builtin_ctzll(kb); kb &= kb - 1; }
      if (kb) { b2 = __builtin_ctzll(kb); kb &= kb - 1; }
      if (kb) { b3 = __builtin_ctzll(kb); kb &= kb - 1; }
      u64 v0 = (lane < 32) ? mb[(size_t)(rb + b0) * 32 + lane] : 0;
      u64 v1 = (b1 >= 0 && lane < 32) ? mb[(size_t)(rb + b1) * 32 + lane] : 0;
      u64 v2 = (b2 >= 0 && lane < 32) ? mb[(size_t)(rb + b2) * 32 + lane] : 0;
      u64 v3 = (b3 >= 0 && lane < 32) ? mb[(size_t)(rb + b3) * 32 + lane] : 0;
      acc0 |= v0; acc1 |= v1; acc2 |= v2; acc3 |= v3;
    }
    intra_cur = intra_nxt;
  }
  __syncthreads();
  if (lane == 0) {
    int run = 0;
    for (int g = 0; g < ngroups; ++g) { pref[g] = run; run += (int)__popcll(keepw[g]); }
    nkept[c] = run;
  }
  __syncthreads();
  // Emit compacted kept keys, re-encoded with ~flat (class + row) in the low word.
  for (int g = 0; g < ngroups; ++g) {
    u64 kw = keepw[g];
    if ((kw >> lane) & 1ull) {
      u64 below = lane ? (kw & ((1ull << lane) - 1ull)) : 0ull;
      int slot = pref[g] + (int)__popcll(below);
      u64 key = skg[(g << 6) + lane];
      u32 r = (~(u32)key) & 2047u;
      u32 flat = (u32)c * R + r;
      atomicOr(&bm[r >> 5], 1u << (r & 31));
      if (slot < 128) lcand[slot] = (key & 0xFFFFFFFF00000000ull) | (u64)(u32)(~flat);
    }
  }
  __syncthreads();
  cand[(size_t)c * 128 + lane] = lcand[lane];
  cand[(size_t)c * 128 + 64 + lane] = lcand[lane + 64];
  keepbm[c * 64 + lane] = bm[lane];
}

// ---------------- final: sort 2560 candidates (pad 4096), write outputs ----------------
__global__ __launch_bounds__(1024) void final_kernel(const u64* __restrict__ cand,
                                                     const int* __restrict__ nkept,
                                                     const u32* __restrict__ keepbm,
                                                     const float* __restrict__ boxes,
                                                     float* __restrict__ out) {
  const int tid = threadIdx.x;
  __shared__ u64 s[4096];  // 32 KB
  __shared__ int nk_sh;
  for (int i = tid; i < 4096; i += 1024) s[i] = (i < K * 128) ? cand[i] : 0ULL;
  if (tid == 0) {
    int nk = 0;
    for (int c = 0; c < K; ++c) nk += nkept[c];
    nk_sh = nk;
  }
  __syncthreads();
  for (int k = 2; k <= 4096; k <<= 1) {
    for (int j = k >> 1; j > 0; j >>= 1) {
      for (int i = tid; i < 4096; i += 1024) {
        int ixj = i ^ j;
        if (ixj > i) {
          u64 a = s[i], b = s[ixj];
          bool sw = ((i & k) == 0) ? (a < b) : (a > b);
          if (sw) { s[i] = b; s[ixj] = a; }
        }
      }
      __syncthreads();
    }
  }
  const int nk = nk_sh;
  if (nk >= TOPK) {
    if (tid < TOPK) {
      u64 key = s[tid];
      u32 flat = ~(u32)key;
      int c = (int)(flat >> 11);
      int r = (int)(flat & 2047);
      float4 b = clipbox(reinterpret_cast<const float4*>(boxes)[r]);
      out[tid] = unmapf((u32)(key >> 32));
      out[100 + 4 * tid + 0] = b.x;
      out[100 + 4 * tid + 1] = b.y;
      out[100 + 4 * tid + 2] = b.z;
      out[100 + 4 * tid + 3] = b.w;
      out[500 + tid] = (float)c;
      out[600 + tid] = (float)r;
    }
  } else {
    // Cold path (not expected on this input): exact -inf padding, flat asc.
    if (tid < nk) {
      u64 key = s[tid];
      u32 flat = ~(u32)key;
      int c = (int)(flat >> 11);
      int r = (int)(flat & 2047);
      float4 b = clipbox(reinterpret_cast<const float4*>(boxes)[r]);
      out[tid] = unmapf((u32)(key >> 32));
      out[100 + 4 * tid + 0] = b.x;
      out[100 + 4 * tid + 1] = b.y;
      out[100 + 4 * tid + 2] = b.z;
      out[100 + 4 * tid + 3] = b.w;
      out[500 + tid] = (float)c;
      out[600 + tid] = (float)r;
    }
    if (tid == 0) {
      int w = nk;
      for (u32 f = 0; f < (u32)(K * R) && w < TOPK; ++f) {
        u32 cc = f >> 11, rr = f & 2047u;
        if (!((keepbm[cc * 64 + (rr >> 5)] >> (rr & 31)) & 1u)) {
          float4 b = clipbox(reinterpret_cast<const float4*>(boxes)[rr]);
          out[w] = -INFINITY;
          out[100 + 4 * w + 0] = b.x;
          out[100 + 4 * w + 1] = b.y;
          out[100 + 4 * w + 2] = b.z;
          out[100 + 4 * w + 3] = b.w;
          out[500 + w] = (float)cc;
          out[600 + w] = (float)rr;
          ++w;
        }
      }
    }
  }
}

extern "C" void kernel_launch(void* const* d_in, const int* in_sizes, int n_in,
                              void* d_out, int out_size, void* d_ws, size_t ws_size,
                              hipStream_t stream) {
  const float* boxes = (const float*)d_in[0];
  const float* scores = (const float*)d_in[1];
  float* out = (float*)d_out;
  char* ws = (char*)d_ws;
  // Workspace layout (~11.6 MB; ws_size >= 11.9 MB confirmed in round 6):
  u64* sortedkey = (u64*)(ws + 0);          //    327680 B (20*2048*8)
  float4* sboxs = (float4*)(ws + 327680);   //    655360 B (20*2048*16)
  int* nvalid = (int*)(ws + 983040);        //       256 B
  u64* maskbuf = (u64*)(ws + 1048576);      //  10485760 B (20*2048*32*8)
  u64* cand = (u64*)(ws + 11534336);        //     20480 B (20*128*8)
  int* nkept = (int*)(ws + 11554816);       //       256 B
  u32* keepbm = (u32*)(ws + 11555072);      //      5120 B (20*64*4)
  (void)in_sizes; (void)n_in; (void)out_size; (void)ws_size;

  sort_kernel<<<K, 1024, 0, stream>>>(scores, boxes, sortedkey, sboxs, nvalid);
  mask_kernel<<<dim3(K, 8), 1024, 0, stream>>>(sboxs, nvalid, maskbuf);
  scan_kernel<<<K, 64, 0, stream>>>(sortedkey, nvalid, maskbuf, cand, nkept, keepbm);
  final_kernel<<<1, 1024, 0, stream>>>(cand, nkept, keepbm, boxes, out);
}

// Round 11
// 322.345 us; speedup vs baseline: 1.2872x; 1.0358x over previous
//
#include <hip/hip_runtime.h>
#include <hip/hip_bf16.h>
#include <math.h>

#define R 2048
#define K 20
#define TOPK 100
#define SCORE_TH 0.5f
#define NMS_TH 0.5f
#define IMGW 1333.0f
#define IMGH 800.0f

typedef unsigned long long u64;
typedef unsigned int u32;

#define MAPF_MINF 0x007FFFFFu  // mapf(-inf)
#define MAPF_TH 0xBF000000u    // mapf(0.5f)

// Monotone map: float total order -> unsigned total order.
__device__ __forceinline__ u32 mapf(float f) {
  u32 b = __float_as_uint(f);
  return (b & 0x80000000u) ? ~b : (b | 0x80000000u);
}
__device__ __forceinline__ float unmapf(u32 u) {
  u32 b = (u & 0x80000000u) ? (u & 0x7FFFFFFFu) : ~u;
  return __uint_as_float(b);
}
__device__ __forceinline__ float4 clipbox(float4 b) {
  float4 o;
  o.x = fminf(fmaxf(b.x, 0.0f), IMGW);
  o.y = fminf(fmaxf(b.y, 0.0f), IMGH);
  o.z = fminf(fmaxf(b.z, 0.0f), IMGW);
  o.w = fminf(fmaxf(b.w, 0.0f), IMGH);
  return o;
}

// ---------------- sort: per-class bitonic (prep fused), 1024 threads ----------------
// Key: (mapf(valid ? s : -inf) << 32) | ~r  -> desc sort == score desc, r asc.
__global__ __launch_bounds__(1024) void sort_kernel(const float* __restrict__ scores,
                                                    const float* __restrict__ boxes,
                                                    u64* __restrict__ sortedkey,
                                                    float4* __restrict__ sboxs,
                                                    int* __restrict__ nvalid) {
  const int c = blockIdx.x;
  const int tid = threadIdx.x;
  __shared__ u64 sk[R];       // 16 KB
  __shared__ float4 cb[R];    // 32 KB
  for (int r = tid; r < R; r += 1024) {
    float4 b = reinterpret_cast<const float4*>(boxes)[r];
    bool fin = isfinite(b.x) && isfinite(b.y) && isfinite(b.z) && isfinite(b.w);
    float s = 0.0f;
    for (int c2 = 0; c2 < K + 1; ++c2) {
      float v = scores[r * (K + 1) + c2];
      fin = fin && isfinite(v);
      if (c2 == c) s = v;
    }
    cb[r] = clipbox(b);
    bool valid = (s > SCORE_TH) && fin;
    u32 hi = valid ? mapf(s) : MAPF_MINF;
    sk[r] = ((u64)hi << 32) | (u32)(~(u32)r);
  }
  __syncthreads();
  for (int k = 2; k <= R; k <<= 1) {
    for (int j = k >> 1; j > 0; j >>= 1) {
      for (int i = tid; i < R; i += 1024) {
        int ixj = i ^ j;
        if (ixj > i) {
          u64 a = sk[i], b = sk[ixj];
          bool sw = ((i & k) == 0) ? (a < b) : (a > b);
          if (sw) { sk[i] = b; sk[ixj] = a; }
        }
      }
      __syncthreads();
    }
  }
  u64* skg = sortedkey + (size_t)c * R;
  float4* sbg = sboxs + (size_t)c * R;
  for (int i = tid; i < R; i += 1024) {
    u64 key = sk[i];
    skg[i] = key;
    u32 r = (~(u32)key) & 2047u;
    sbg[i] = cb[r];
    bool vi = ((u32)(key >> 32)) > MAPF_TH;
    if (i == 0 && !vi) nvalid[c] = 0;
    if (vi) {
      bool vlast = (i == R - 1);
      bool vn = vlast ? false : (((u32)(sk[i + 1] >> 32)) > MAPF_TH);
      if (vlast || !vn) nvalid[c] = i + 1;
    }
  }
}

// ---------------- mask: suppression bit-matrix + contiguous intra array ----------------
// mask[c][i][w] bit b: j = 64w+b, j > i, iou(i,j) > TH.  Rows >= nv never read.
// intrabuf[c][i] = diagonal word (word i>>6) of row i, stored contiguously.
__global__ __launch_bounds__(1024) void mask_kernel(const float4* __restrict__ sboxs,
                                                    const int* __restrict__ nvalid,
                                                    u64* __restrict__ maskbuf,
                                                    u64* __restrict__ intrabuf) {
  const int c = blockIdx.x;
  const int tid = threadIdx.x;
  const int lane = tid & 63;
  const int wave = tid >> 6;  // 0..15
  __shared__ float4 sb[R];
  __shared__ float sa[R];
  const float4* sbg = sboxs + (size_t)c * R;
  const int nv = nvalid[c];
  for (int i = tid; i < R; i += 1024) {
    float4 b = sbg[i];
    sb[i] = b;
    sa[i] = (b.z - b.x) * (b.w - b.y);
  }
  __syncthreads();
  const int wend = (nv + 63) >> 6;
  u64* mrowbase = maskbuf + (size_t)c * R * 32;
  u64* ibase = intrabuf + (size_t)c * R;
  for (int row = blockIdx.y * 16 + wave; row < nv; row += 128) {
    float4 b = sb[row];
    float ai = sa[row];
    u64 myword = 0;
    int wstart = row >> 6;
    for (int w = wstart; w < wend; ++w) {
      int col = (w << 6) + lane;
      float4 q = sb[col];
      float lx = fmaxf(b.x, q.x), ly = fmaxf(b.y, q.y);
      float rx = fminf(b.z, q.z), ry = fminf(b.w, q.w);
      float ww = fmaxf(rx - lx, 0.0f), hh = fmaxf(ry - ly, 0.0f);
      float inter = ww * hh;
      float uni = ai + sa[col] - inter;
      bool bit = (col > row) && (inter / fmaxf(uni, 1e-9f) > NMS_TH);
      u64 word = __ballot(bit);
      if (lane == w) myword = word;  // lane w keeps word w (w < 32)
    }
    u64* mrow = mrowbase + (size_t)row * 32;
    if (lane < 32) mrow[lane] = myword;  // words outside [wstart,wend) are 0
    if (lane == wstart) ibase[row] = myword;  // diagonal word, contiguous
  }
}

// ---------------- scan: sequential greedy, contiguous intra, parallel kept ORs -----
// Bit-identical greedy semantics (round-9/10-proven inner loop): suppression of
// row b = (cross-group word at group start, via one shfl) OR (intra words of prior
// kept rows in this group, via register shfl). Kept rows' full mask rows OR into
// the distributed acc at group end: up to 8 independent loads in flight per chunk
// (named slots; single wait per chunk), consumed only at the next group boundary.
__global__ __launch_bounds__(64) void scan_kernel(const u64* __restrict__ sortedkey,
                                                  const int* __restrict__ nvalid,
                                                  const u64* __restrict__ maskbuf,
                                                  const u64* __restrict__ intrabuf,
                                                  u64* __restrict__ cand,
                                                  int* __restrict__ nkept,
                                                  u32* __restrict__ keepbm) {
  const int c = blockIdx.x;
  const int lane = threadIdx.x;
  const int nv = nvalid[c];
  const u64* mb = maskbuf + (size_t)c * R * 32;
  const u64* ib = intrabuf + (size_t)c * R;
  const u64* skg = sortedkey + (size_t)c * R;
  __shared__ u64 keepw[32];
  __shared__ int pref[32];
  __shared__ u64 lcand[128];
  __shared__ u32 bm[64];
  if (lane < 32) keepw[lane] = 0;
  bm[lane] = 0;
  lcand[lane] = 0;
  lcand[lane + 64] = 0;
  __syncthreads();

  const int ngroups = (nv + 63) >> 6;
  u64 acc = 0;  // distributed suppression bitmap: lane w (<32) owns word w
  // Prefetch group 0's intra words (contiguous: 512 B per group).
  u64 intra_cur = (ngroups > 0 && lane < nv) ? ib[lane] : 0;

  for (int g = 0; g < ngroups; ++g) {
    const int rb = g << 6;
    int rend = nv - rb; if (rend > 64) rend = 64;
    // Prefetch next group's intra words (off-chain; consumed next iteration).
    u64 intra_nxt = 0;
    if (g + 1 < ngroups) {
      int row = rb + 64 + lane;
      intra_nxt = (row < nv) ? ib[row] : 0;
    }
    // Cross-group suppression word for this group (uniform after shfl).
    u64 rg = __shfl(acc, g, 64);
    u64 keep = 0;
    for (int b = 0; b < rend; ++b) {        // proven serial loop: register-only tests
      if (!((rg >> b) & 1ull)) {
        keep |= (1ull << b);
        rg |= __shfl(intra_cur, b, 64);     // intra suppressions of kept row b (bits > b)
      }
    }
    if (lane == 0) keepw[g] = keep;
    // Parallel kept-row ORs: chunks of up to 8 independent loads, one wait each.
    u64 kb = keep;
    while (kb) {
      int b0 = __builtin_ctzll(kb); kb &= kb - 1;
      int b1 = -1, b2 = -1, b3 = -1, b4 = -1, b5 = -1, b6 = -1, b7 = -1;
      if (kb) { b1 = __builtin_ctzll(kb); kb &= kb - 1; }
      if (kb) { b2 = __builtin_ctzll(kb); kb &= kb - 1; }
      if (kb) { b3 = __builtin_ctzll(kb); kb &= kb - 1; }
      if (kb) { b4 = __builtin_ctzll(kb); kb &= kb - 1; }
      if (kb) { b5 = __builtin_ctzll(kb); kb &= kb - 1; }
      if (kb) { b6 = __builtin_ctzll(kb); kb &= kb - 1; }
      if (kb) { b7 = __builtin_ctzll(kb); kb &= kb - 1; }
      // Clamp absent slots to b0 (valid row) and mask their contribution out.
      int i1 = (b1 >= 0) ? b1 : b0, i2 = (b2 >= 0) ? b2 : b0, i3 = (b3 >= 0) ? b3 : b0;
      int i4 = (b4 >= 0) ? b4 : b0, i5 = (b5 >= 0) ? b5 : b0, i6 = (b6 >= 0) ? b6 : b0;
      int i7 = (b7 >= 0) ? b7 : b0;
      u64 m1 = (b1 >= 0) ? ~0ull : 0ull, m2 = (b2 >= 0) ? ~0ull : 0ull;
      u64 m3 = (b3 >= 0) ? ~0ull : 0ull, m4 = (b4 >= 0) ? ~0ull : 0ull;
      u64 m5 = (b5 >= 0) ? ~0ull : 0ull, m6 = (b6 >= 0) ? ~0ull : 0ull;
      u64 m7 = (b7 >= 0) ? ~0ull : 0ull;
      u64 v0 = (lane < 32) ? mb[(size_t)(rb + b0) * 32 + lane] : 0;
      u64 v1 = (lane < 32) ? mb[(size_t)(rb + i1) * 32 + lane] : 0;
      u64 v2 = (lane < 32) ? mb[(size_t)(rb + i2) * 32 + lane] : 0;
      u64 v3 = (lane < 32) ? mb[(size_t)(rb + i3) * 32 + lane] : 0;
      u64 v4 = (lane < 32) ? mb[(size_t)(rb + i4) * 32 + lane] : 0;
      u64 v5 = (lane < 32) ? mb[(size_t)(rb + i5) * 32 + lane] : 0;
      u64 v6 = (lane < 32) ? mb[(size_t)(rb + i6) * 32 + lane] : 0;
      u64 v7 = (lane < 32) ? mb[(size_t)(rb + i7) * 32 + lane] : 0;
      acc |= v0 | (v1 & m1) | (v2 & m2) | (v3 & m3) |
             (v4 & m4) | (v5 & m5) | (v6 & m6) | (v7 & m7);
    }
    intra_cur = intra_nxt;
  }
  __syncthreads();
  if (lane == 0) {
    int run = 0;
    for (int g = 0; g < ngroups; ++g) { pref[g] = run; run += (int)__popcll(keepw[g]); }
    nkept[c] = run;
  }
  __syncthreads();
  // Emit compacted kept keys, re-encoded with ~flat (class + row) in the low word.
  for (int g = 0; g < ngroups; ++g) {
    u64 kw = keepw[g];
    if ((kw >> lane) & 1ull) {
      u64 below = lane ? (kw & ((1ull << lane) - 1ull)) : 0ull;
      int slot = pref[g] + (int)__popcll(below);
      u64 key = skg[(g << 6) + lane];
      u32 r = (~(u32)key) & 2047u;
      u32 flat = (u32)c * R + r;
      atomicOr(&bm[r >> 5], 1u << (r & 31));
      if (slot < 128) lcand[slot] = (key & 0xFFFFFFFF00000000ull) | (u64)(u32)(~flat);
    }
  }
  __syncthreads();
  cand[(size_t)c * 128 + lane] = lcand[lane];
  cand[(size_t)c * 128 + 64 + lane] = lcand[lane + 64];
  keepbm[c * 64 + lane] = bm[lane];
}

// ---------------- final: sort 2560 candidates (pad 4096), write outputs ----------------
__global__ __launch_bounds__(1024) void final_kernel(const u64* __restrict__ cand,
                                                     const int* __restrict__ nkept,
                                                     const u32* __restrict__ keepbm,
                                                     const float* __restrict__ boxes,
                                                     float* __restrict__ out) {
  const int tid = threadIdx.x;
  __shared__ u64 s[4096];  // 32 KB
  __shared__ int nk_sh;
  for (int i = tid; i < 4096; i += 1024) s[i] = (i < K * 128) ? cand[i] : 0ULL;
  if (tid == 0) {
    int nk = 0;
    for (int c = 0; c < K; ++c) nk += nkept[c];
    nk_sh = nk;
  }
  __syncthreads();
  for (int k = 2; k <= 4096; k <<= 1) {
    for (int j = k >> 1; j > 0; j >>= 1) {
      for (int i = tid; i < 4096; i += 1024) {
        int ixj = i ^ j;
        if (ixj > i) {
          u64 a = s[i], b = s[ixj];
          bool sw = ((i & k) == 0) ? (a < b) : (a > b);
          if (sw) { s[i] = b; s[ixj] = a; }
        }
      }
      __syncthreads();
    }
  }
  const int nk = nk_sh;
  if (nk >= TOPK) {
    if (tid < TOPK) {
      u64 key = s[tid];
      u32 flat = ~(u32)key;
      int c = (int)(flat >> 11);
      int r = (int)(flat & 2047);
      float4 b = clipbox(reinterpret_cast<const float4*>(boxes)[r]);
      out[tid] = unmapf((u32)(key >> 32));
      out[100 + 4 * tid + 0] = b.x;
      out[100 + 4 * tid + 1] = b.y;
      out[100 + 4 * tid + 2] = b.z;
      out[100 + 4 * tid + 3] = b.w;
      out[500 + tid] = (float)c;
      out[600 + tid] = (float)r;
    }
  } else {
    // Cold path (not expected on this input): exact -inf padding, flat asc.
    if (tid < nk) {
      u64 key = s[tid];
      u32 flat = ~(u32)key;
      int c = (int)(flat >> 11);
      int r = (int)(flat & 2047);
      float4 b = clipbox(reinterpret_cast<const float4*>(boxes)[r]);
      out[tid] = unmapf((u32)(key >> 32));
      out[100 + 4 * tid + 0] = b.x;
      out[100 + 4 * tid + 1] = b.y;
      out[100 + 4 * tid + 2] = b.z;
      out[100 + 4 * tid + 3] = b.w;
      out[500 + tid] = (float)c;
      out[600 + tid] = (float)r;
    }
    if (tid == 0) {
      int w = nk;
      for (u32 f = 0; f < (u32)(K * R) && w < TOPK; ++f) {
        u32 cc = f >> 11, rr = f & 2047u;
        if (!((keepbm[cc * 64 + (rr >> 5)] >> (rr & 31)) & 1u)) {
          float4 b = clipbox(reinterpret_cast<const float4*>(boxes)[rr]);
          out[w] = -INFINITY;
          out[100 + 4 * w + 0] = b.x;
          out[100 + 4 * w + 1] = b.y;
          out[100 + 4 * w + 2] = b.z;
          out[100 + 4 * w + 3] = b.w;
          out[500 + w] = (float)cc;
          out[600 + w] = (float)rr;
          ++w;
        }
      }
    }
  }
}

extern "C" void kernel_launch(void* const* d_in, const int* in_sizes, int n_in,
                              void* d_out, int out_size, void* d_ws, size_t ws_size,
                              hipStream_t stream) {
  const float* boxes = (const float*)d_in[0];
  const float* scores = (const float*)d_in[1];
  float* out = (float*)d_out;
  char* ws = (char*)d_ws;
  // Workspace layout (~11.9 MB; ws_size >= 11,908,096 confirmed in round 6):
  u64* sortedkey = (u64*)(ws + 0);          //    327680 B (20*2048*8)
  float4* sboxs = (float4*)(ws + 327680);   //    655360 B (20*2048*16)
  int* nvalid = (int*)(ws + 983040);        //       256 B
  u64* maskbuf = (u64*)(ws + 1048576);      //  10485760 B (20*2048*32*8)
  u64* cand = (u64*)(ws + 11534336);        //     20480 B (20*128*8)
  int* nkept = (int*)(ws + 11554816);       //       256 B
  u32* keepbm = (u32*)(ws + 11555072);      //      5120 B (20*64*4)
  u64* intrabuf = (u64*)(ws + 11560192);    //    327680 B (20*2048*8) -> ends 11887872
  (void)in_sizes; (void)n_in; (void)out_size; (void)ws_size;

  sort_kernel<<<K, 1024, 0, stream>>>(scores, boxes, sortedkey, sboxs, nvalid);
  mask_kernel<<<dim3(K, 8), 1024, 0, stream>>>(sboxs, nvalid, maskbuf, intrabuf);
  scan_kernel<<<K, 64, 0, stream>>>(sortedkey, nvalid, maskbuf, intrabuf, cand, nkept, keepbm);
  final_kernel<<<1, 1024, 0, stream>>>(cand, nkept, keepbm, boxes, out);
}